// Round 9
// baseline (359.955 us; speedup 1.0000x reference)
//
#include <hip/hip_runtime.h>
#include <cstdint>
#include <cstddef>

typedef __bf16 bf16x8 __attribute__((ext_vector_type(8)));
typedef float f32x4 __attribute__((ext_vector_type(4)));
typedef float f32x16 __attribute__((ext_vector_type(16)));
typedef unsigned int u32x2v __attribute__((ext_vector_type(2)));
typedef unsigned short u16;

constexpr int S_LEN  = 2048;
constexpr int DMODEL = 2048;
constexpr int NHEAD  = 16;
constexpr int HDIM   = 128;
constexpr int WIN    = 512;

#define AS1 __attribute__((address_space(1)))
#define AS3 __attribute__((address_space(3)))

__device__ __forceinline__ u16 f2bf(float f) {
  union { float ff; uint32_t u; } a; a.ff = f;
  return (u16)((a.u + 0x7fffu + ((a.u >> 16) & 1u)) >> 16);  // RNE
}

__device__ __forceinline__ uint32_t cvtpk(float lo, float hi) {
  uint32_t r;
  asm("v_cvt_pk_bf16_f32 %0, %1, %2" : "=v"(r) : "v"(lo), "v"(hi));
  return r;
}

// ---------------- fused fp32 -> bf16 convert ----------------
__global__ void cvt_all(const float* __restrict__ x,  const float* __restrict__ wq,
                        const float* __restrict__ wk, const float* __restrict__ wv,
                        const float* __restrict__ wo,
                        u16* __restrict__ xb,  u16* __restrict__ wqb,
                        u16* __restrict__ wkb, u16* __restrict__ wvb,
                        u16* __restrict__ wob) {
  const int total = 6291456;
  int i = blockIdx.x * blockDim.x + threadIdx.x;
  const int stride = gridDim.x * blockDim.x;
  for (; i < total; i += stride) {
    const int r = i >> 20;
    const float* src; u16* dst; int off;
    if (r < 2)       { src = x;  dst = xb;  off = i; }
    else if (r == 2) { src = wq; dst = wqb; off = i - (2 << 20); }
    else if (r == 3) { src = wk; dst = wkb; off = i - (3 << 20); }
    else if (r == 4) { src = wv; dst = wvb; off = i - (4 << 20); }
    else             { src = wo; dst = wob; off = i - (5 << 20); }
    float4 v = reinterpret_cast<const float4*>(src)[off];
    uint2 pk;
    pk.x = (uint32_t)f2bf(v.x) | ((uint32_t)f2bf(v.y) << 16);
    pk.y = (uint32_t)f2bf(v.z) | ((uint32_t)f2bf(v.w) << 16);
    reinterpret_cast<uint2*>(dst)[off] = pk;
  }
}

// ---------------- rope tables ----------------
__global__ void rope_kernel(float* __restrict__ rc, float* __restrict__ rs) {
  const int i = blockIdx.x * blockDim.x + threadIdx.x;
  const int s = i >> 6, f = i & 63;
  const double inv = exp(-(double)f * (log(10000.0) / 64.0));
  const double a = (double)s * inv;
  rc[i] = (float)cos(a);
  rs[i] = (float)sin(a);
}

// ---------------- QKV GEMM: 128x192 tile, BK=128, 2-phase, frag-linear LDS ----------------
// B = contiguous [Wq;Wk;Wv] (6144x2048). grid (32,32) = 1024 = 2 exact rounds @ 2 blocks/CU.
// 4 waves (2Mx2N), wave-tile 64x96. LDS 80KB single-buffer (A 32KB + B 48KB).
// 16 K-iterations (half of r3's 32 -> half the vmcnt(0)+barrier drains).
// Fragment-linear LDS: A unit ((kc*8+rf)*4+lk)*16+lr, B unit ((kc*12+cf)*4+lk)*16+lr
// -> ds_read_b128 per wave is perfectly linear (ZERO bank conflicts).
__global__ __launch_bounds__(256, 2)
void gemm_qkv(const u16* __restrict__ A, const u16* __restrict__ Bcat,
              u16* __restrict__ qout, u16* __restrict__ kout, u16* __restrict__ vtout,
              const float* __restrict__ rc, const float* __restrict__ rs) {
  constexpr int K = DMODEL;
  __shared__ __align__(16) u16 sm[5120 * 8];     // A 2048 units + B 3072 units (16B each)

  const int ct = blockIdx.x, mt = blockIdx.y;
  const int brow = mt * 128;
  const int bcol = ct * 192;

  const int tid = threadIdx.x;
  const int w = tid >> 6, lane = tid & 63;
  const int lr = lane & 15, lk = lane >> 4;
  const int wm = w >> 1, wn = w & 1;

  const u16* Ag = A    + (size_t)brow * K;
  const u16* Bg = Bcat + (size_t)bcol * K;

  f32x4 acc[4][6] = {};

  for (int k0 = 0; k0 < K; k0 += 128) {
    // ---- stage A: 2048 units, 8 per thread ----
#pragma unroll
    for (int i = 0; i < 8; ++i) {
      const int u = i * 256 + tid;
      const int ulr = u & 15, ulk = (u >> 4) & 3, urf = (u >> 6) & 7, ukc = (u >> 9) & 3;
      const u16* src = Ag + (size_t)(urf * 16 + ulr) * K + k0 + ukc * 32 + ulk * 8;
      __builtin_amdgcn_global_load_lds((const AS1 void*)src,
          (AS3 void*)(&sm[(i * 256 + w * 64) * 8]), 16, 0, 0);
    }
    // ---- stage B: 3072 units, 12 per thread ----
#pragma unroll
    for (int i = 0; i < 12; ++i) {
      const int u = i * 256 + tid;
      const int ulr = u & 15, ulk = (u >> 4) & 3, t = u >> 6;
      const int ucf = t % 12, ukc = t / 12;
      const u16* src = Bg + (size_t)(ucf * 16 + ulr) * K + k0 + ukc * 32 + ulk * 8;
      __builtin_amdgcn_global_load_lds((const AS1 void*)src,
          (AS3 void*)(&sm[(2048 + i * 256 + w * 64) * 8]), 16, 0, 0);
    }
    __syncthreads();
#pragma unroll
    for (int kc = 0; kc < 4; ++kc) {
      bf16x8 a[4], b[6];
#pragma unroll
      for (int mf = 0; mf < 4; ++mf)
        a[mf] = *reinterpret_cast<const bf16x8*>(
            &sm[(((kc * 8 + wm * 4 + mf) * 4 + lk) * 16 + lr) * 8]);
#pragma unroll
      for (int nf = 0; nf < 6; ++nf)
        b[nf] = *reinterpret_cast<const bf16x8*>(
            &sm[(2048 + ((kc * 12 + wn * 6 + nf) * 4 + lk) * 16 + lr) * 8]);
#pragma unroll
      for (int mf = 0; mf < 4; ++mf)
#pragma unroll
        for (int nf = 0; nf < 6; ++nf)
          acc[mf][nf] = __builtin_amdgcn_mfma_f32_16x16x32_bf16(a[mf], b[nf], acc[mf][nf], 0, 0, 0);
    }
    __syncthreads();
  }

  // ---- epilogue ----  C frag: col = lane&15, row = lk*4 + j (m89). Region per 16-col frag.
#pragma unroll
  for (int mf = 0; mf < 4; ++mf) {
    const int gm0 = brow + wm * 64 + mf * 16 + lk * 4;
    const int b_ = gm0 >> 11, s0 = gm0 & 2047;
#pragma unroll
    for (int nf = 0; nf < 6; ++nf) {
      const int gn = bcol + wn * 96 + nf * 16 + lr;      // 0..6143 over [Q|K|V]
      const int reg = gn >> 11;
      const int h = (gn >> 7) & 15, dh = gn & 127;
      if (reg == 2) {              // V: transposed [B,H,Dh,S] bf16
        uint2 pk;
        pk.x = (uint32_t)f2bf(acc[mf][nf][0]) | ((uint32_t)f2bf(acc[mf][nf][1]) << 16);
        pk.y = (uint32_t)f2bf(acc[mf][nf][2]) | ((uint32_t)f2bf(acc[mf][nf][3]) << 16);
        *reinterpret_cast<uint2*>(&vtout[((size_t)((b_ * NHEAD + h) * HDIM + dh)) * S_LEN + s0]) = pk;
      } else {                     // Q/K: rope (+scale for Q), packed u32 stores
        u16* QK = reg == 0 ? qout : kout;
        const int fi = dh >> 1;
        const bool ev = (dh & 1) == 0;
#pragma unroll
        for (int j = 0; j < 4; ++j) {
          float v = acc[mf][nf][j];
          float pp = __shfl_xor(v, 1, 64);               // partner channel (dh^1)
          const float c  = rc[(s0 + j) * 64 + fi];
          const float sn = rs[(s0 + j) * 64 + fi];
          float oo = ev ? (v * c - pp * sn) : (pp * sn + v * c);
          if (reg == 0) oo *= 0.08838834764831845f;      // Dh^-0.5
          const float op = __shfl_xor(oo, 1, 64);        // partner's rope'd value
          if (ev) {
            const uint32_t pk = (uint32_t)f2bf(oo) | ((uint32_t)f2bf(op) << 16);
            *reinterpret_cast<uint32_t*>(
                &QK[((size_t)(b_ * NHEAD + h) * S_LEN + (s0 + j)) * HDIM + dh]) = pk;
          }
        }
      }
    }
  }
}

// ---------------- O projection: 128x128 tile, BK=128, 2-phase, frag-linear LDS ----------------
// grid (16,32) = 512 = single round @ 2 blocks/CU. LDS 64KB.
__global__ __launch_bounds__(256, 2)
void gemm_o(const u16* __restrict__ A, const u16* __restrict__ Bw,
            float* __restrict__ O) {
  constexpr int K = DMODEL;
  __shared__ __align__(16) u16 sm[4096 * 8];     // A 2048 + B 2048 units

  const int brow = blockIdx.y * 128;
  const int bcol = blockIdx.x * 128;

  const int tid = threadIdx.x;
  const int w = tid >> 6, lane = tid & 63;
  const int lr = lane & 15, lk = lane >> 4;
  const int wm = w >> 1, wn = w & 1;

  const u16* Ag = A  + (size_t)brow * K;
  const u16* Bg = Bw + (size_t)bcol * K;

  f32x4 acc[4][4] = {};

  for (int k0 = 0; k0 < K; k0 += 128) {
#pragma unroll
    for (int i = 0; i < 8; ++i) {      // A: 2048 units
      const int u = i * 256 + tid;
      const int ulr = u & 15, ulk = (u >> 4) & 3, urf = (u >> 6) & 7, ukc = (u >> 9) & 3;
      const u16* src = Ag + (size_t)(urf * 16 + ulr) * K + k0 + ukc * 32 + ulk * 8;
      __builtin_amdgcn_global_load_lds((const AS1 void*)src,
          (AS3 void*)(&sm[(i * 256 + w * 64) * 8]), 16, 0, 0);
    }
#pragma unroll
    for (int i = 0; i < 8; ++i) {      // B: 2048 units
      const int u = i * 256 + tid;
      const int ulr = u & 15, ulk = (u >> 4) & 3, urf = (u >> 6) & 7, ukc = (u >> 9) & 3;
      const u16* src = Bg + (size_t)(urf * 16 + ulr) * K + k0 + ukc * 32 + ulk * 8;
      __builtin_amdgcn_global_load_lds((const AS1 void*)src,
          (AS3 void*)(&sm[(2048 + i * 256 + w * 64) * 8]), 16, 0, 0);
    }
    __syncthreads();
#pragma unroll
    for (int kc = 0; kc < 4; ++kc) {
      bf16x8 a[4], b[4];
#pragma unroll
      for (int mf = 0; mf < 4; ++mf)
        a[mf] = *reinterpret_cast<const bf16x8*>(
            &sm[(((kc * 8 + wm * 4 + mf) * 4 + lk) * 16 + lr) * 8]);
#pragma unroll
      for (int nf = 0; nf < 4; ++nf)
        b[nf] = *reinterpret_cast<const bf16x8*>(
            &sm[(2048 + ((kc * 8 + wn * 4 + nf) * 4 + lk) * 16 + lr) * 8]);
#pragma unroll
      for (int mf = 0; mf < 4; ++mf)
#pragma unroll
        for (int nf = 0; nf < 4; ++nf)
          acc[mf][nf] = __builtin_amdgcn_mfma_f32_16x16x32_bf16(a[mf], b[nf], acc[mf][nf], 0, 0, 0);
    }
    __syncthreads();
  }

#pragma unroll
  for (int mf = 0; mf < 4; ++mf) {
    const int gm0 = brow + wm * 64 + mf * 16 + lk * 4;
#pragma unroll
    for (int nf = 0; nf < 4; ++nf) {
      const int gn = bcol + wn * 64 + nf * 16 + lr;
#pragma unroll
      for (int j = 0; j < 4; ++j)
        O[(size_t)(gm0 + j) * DMODEL + gn] = acc[mf][nf][j];
    }
  }
}

// ---------------- sliding-window flash attention, LDS-staged K/V (r3-proven) ----------------
__global__ __launch_bounds__(256, 2)
void swa3_kernel(const u16* __restrict__ Qp, const u16* __restrict__ Kp,
                 const u16* __restrict__ Vt, u16* __restrict__ AO) {
  __shared__ __align__(16) u16 Ksh[2][64 * 128];
  __shared__ __align__(16) u16 Vsh[2][128 * 64];

  const int lin = blockIdx.x + gridDim.x * blockIdx.y;
  const int slot = lin >> 3;
  const int bh = (lin & 7) * 4 + (slot >> 4);
  const int qt = slot & 15;

  const int w = threadIdx.x >> 6;
  const int lane = threadIdx.x & 63;
  const int lq = lane & 31, hi = lane >> 5;
  const int qb_blk = qt * 128;
  const int qw = qb_blk + w * 32;
  const int qq = qw + lq;

  const u16* Qb = Qp + (size_t)bh * S_LEN * HDIM;
  const u16* Kb = Kp + (size_t)bh * S_LEN * HDIM;
  const u16* Vb = Vt + (size_t)bh * HDIM * S_LEN;

  bf16x8 qf[8];
#pragma unroll
  for (int s = 0; s < 8; ++s)
    qf[s] = *reinterpret_cast<const bf16x8*>(&Qb[(size_t)qq * HDIM + s * 16 + hi * 8]);

  f32x16 ot[4] = {};
  float m = 0.f, lsum = 0.f;

  const int c_lo = (qb_blk >= WIN) ? qb_blk - WIN : 0;
  const int c_hi = qb_blk + 128;

  auto stage = [&](int buf, int kc) {
#pragma unroll
    for (int i = 0; i < 4; ++i) {
      const int u = i * 256 + w * 64 + lane;
      const int row = u >> 4, sl = (u & 15) ^ (row & 7);
      __builtin_amdgcn_global_load_lds(
          (const AS1 void*)(Kb + (size_t)(kc + row) * HDIM + sl * 8),
          (AS3 void*)(&Ksh[buf][(size_t)(i * 256 + w * 64) * 8]), 16, 0, 0);
    }
#pragma unroll
    for (int i = 0; i < 4; ++i) {
      const int u = i * 256 + w * 64 + lane;
      const int row = u >> 3, sl = (u & 7) ^ (row & 7);
      __builtin_amdgcn_global_load_lds(
          (const AS1 void*)(Vb + (size_t)row * S_LEN + kc + sl * 8),
          (AS3 void*)(&Vsh[buf][(size_t)(i * 256 + w * 64) * 8]), 16, 0, 0);
    }
  };

  int buf = 0;
  stage(0, c_lo);
  __syncthreads();

  for (int kc = c_lo; kc < c_hi; kc += 64, buf ^= 1) {
    if (kc + 64 < c_hi) stage(buf ^ 1, kc + 64);

#pragma unroll
    for (int half = 0; half < 2; ++half) {
      const int kch = kc + half * 32;
      if (kch > qw + 31 || kch < qw - 542) continue;

      f32x16 P = {};
#pragma unroll
      for (int s = 0; s < 8; ++s) {
        const int row = half * 32 + lq;
        const int byte = row * 256 + ((s * 32 + hi * 16) ^ ((row & 7) << 4));
        bf16x8 kf = *reinterpret_cast<const bf16x8*>(&Ksh[buf][byte >> 1]);
        P = __builtin_amdgcn_mfma_f32_32x32x16_bf16(kf, qf[s], P, 0, 0, 0);
      }

      const bool needmask = (kch + 32 > qw) || (qw + 31 - kch >= WIN);
      float p[16];
      float pmax = -1e30f;
#pragma unroll
      for (int r = 0; r < 16; ++r) {
        float v = P[r];
        if (needmask) {
          const int kk = kch + (r & 3) + ((r >> 2) << 3) + hi * 4;
          const bool keep = (qq >= kk) && (qq - kk < WIN);
          v = keep ? v : -1e30f;
        }
        p[r] = v;
        pmax = fmaxf(pmax, v);
      }

      if (__any(pmax - m > 8.f)) {
        const float rm = fmaxf(pmax, __shfl_xor(pmax, 32, 64));
        const float mnew = fmaxf(m, rm);
        const float alpha = __expf(m - mnew);
        lsum *= alpha;
#pragma unroll
        for (int dt = 0; dt < 4; ++dt)
#pragma unroll
          for (int r = 0; r < 16; ++r) ot[dt][r] *= alpha;
        m = mnew;
      }

      float ls = 0.f;
#pragma unroll
      for (int r = 0; r < 16; ++r) {
        p[r] = __expf(p[r] - m);
        ls += p[r];
      }
      lsum += ls;

      uint32_t W[8];
#pragma unroll
      for (int i = 0; i < 8; ++i) W[i] = cvtpk(p[2 * i], p[2 * i + 1]);
      u32x2v r02 = __builtin_amdgcn_permlane32_swap(W[0], W[2], false, false);
      u32x2v r13 = __builtin_amdgcn_permlane32_swap(W[1], W[3], false, false);
      u32x2v r46 = __builtin_amdgcn_permlane32_swap(W[4], W[6], false, false);
      u32x2v r57 = __builtin_amdgcn_permlane32_swap(W[5], W[7], false, false);

#pragma unroll
      for (int ks = 0; ks < 2; ++ks) {
        union { uint32_t u[4]; bf16x8 v; } pb;
        if (ks == 0) { pb.u[0] = r02[0]; pb.u[1] = r13[0]; pb.u[2] = r02[1]; pb.u[3] = r13[1]; }
        else         { pb.u[0] = r46[0]; pb.u[1] = r57[0]; pb.u[2] = r46[1]; pb.u[3] = r57[1]; }
#pragma unroll
        for (int dt = 0; dt < 4; ++dt) {
          const int d = dt * 32 + lq;
          const int byte = d * 128 + ((half * 64 + ks * 32 + hi * 16) ^ ((d & 7) << 4));
          bf16x8 vf = *reinterpret_cast<const bf16x8*>(&Vsh[buf][byte >> 1]);
          ot[dt] = __builtin_amdgcn_mfma_f32_32x32x16_bf16(vf, pb.v, ot[dt], 0, 0, 0);
        }
      }
    }
    __syncthreads();
  }

  const float lf = lsum + __shfl_xor(lsum, 32, 64);
  const float inv = 1.f / lf;
  const int b = bh >> 4, h = bh & 15;
  u16* Ob = AO + (size_t)(b * S_LEN + qq) * DMODEL + h * HDIM;
#pragma unroll
  for (int dt = 0; dt < 4; ++dt)
#pragma unroll
    for (int rq = 0; rq < 4; ++rq) {
      uint2 pk;
      pk.x = cvtpk(ot[dt][rq * 4 + 0] * inv, ot[dt][rq * 4 + 1] * inv);
      pk.y = cvtpk(ot[dt][rq * 4 + 2] * inv, ot[dt][rq * 4 + 3] * inv);
      *reinterpret_cast<uint2*>(&Ob[dt * 32 + rq * 8 + hi * 4]) = pk;
    }
}

extern "C" void kernel_launch(void* const* d_in, const int* in_sizes, int n_in,
                              void* d_out, int out_size, void* d_ws, size_t ws_size,
                              hipStream_t stream) {
  const float* x  = (const float*)d_in[0];
  const float* Wq = (const float*)d_in[1];
  const float* Wk = (const float*)d_in[2];
  const float* Wv = (const float*)d_in[3];
  const float* Wo = (const float*)d_in[4];
  float* out = (float*)d_out;

  u16* p = (u16*)d_ws;
  u16* xb  = p; p += (size_t)4096 * 2048;
  u16* wqb = p; p += (size_t)2048 * 2048;   // wqb,wkb,wvb contiguous = Bcat [6144,2048]
  u16* wkb = p; p += (size_t)2048 * 2048;
  u16* wvb = p; p += (size_t)2048 * 2048;
  u16* wob = p; p += (size_t)2048 * 2048;
  u16* qb  = p; p += (size_t)32 * 2048 * 128;
  u16* kb  = p; p += (size_t)32 * 2048 * 128;
  u16* vtb = p; p += (size_t)32 * 128 * 2048;
  u16* aob = p; p += (size_t)4096 * 2048;
  float* rc = (float*)p;
  float* rs = rc + (size_t)2048 * 64;

  cvt_all<<<3072, 256, 0, stream>>>(x, Wq, Wk, Wv, Wo, xb, wqb, wkb, wvb, wob);
  rope_kernel<<<512, 256, 0, stream>>>(rc, rs);
  gemm_qkv<<<dim3(32, 32), 256, 0, stream>>>(xb, wqb, qb, kb, vtb, rc, rs);
  swa3_kernel<<<dim3(16, 32), 256, 0, stream>>>(qb, kb, vtb, aob);
  gemm_o<<<dim3(16, 32), 256, 0, stream>>>(aob, wob, out);
}

// Round 10
// 260.672 us; speedup vs baseline: 1.3809x; 1.3809x over previous
//
#include <hip/hip_runtime.h>
#include <cstdint>
#include <cstddef>

typedef __bf16 bf16x8 __attribute__((ext_vector_type(8)));
typedef float f32x4 __attribute__((ext_vector_type(4)));
typedef float f32x16 __attribute__((ext_vector_type(16)));
typedef unsigned int u32x2v __attribute__((ext_vector_type(2)));
typedef unsigned short u16;

constexpr int S_LEN  = 2048;
constexpr int DMODEL = 2048;
constexpr int NHEAD  = 16;
constexpr int HDIM   = 128;
constexpr int WIN    = 512;

#define AS1 __attribute__((address_space(1)))
#define AS3 __attribute__((address_space(3)))

__device__ __forceinline__ u16 f2bf(float f) {
  union { float ff; uint32_t u; } a; a.ff = f;
  return (u16)((a.u + 0x7fffu + ((a.u >> 16) & 1u)) >> 16);  // RNE
}

__device__ __forceinline__ uint32_t cvtpk(float lo, float hi) {
  uint32_t r;
  asm("v_cvt_pk_bf16_f32 %0, %1, %2" : "=v"(r) : "v"(lo), "v"(hi));
  return r;
}

// ---------------- fused fp32 -> bf16 convert ----------------
__global__ void cvt_all(const float* __restrict__ x,  const float* __restrict__ wq,
                        const float* __restrict__ wk, const float* __restrict__ wv,
                        const float* __restrict__ wo,
                        u16* __restrict__ xb,  u16* __restrict__ wqb,
                        u16* __restrict__ wkb, u16* __restrict__ wvb,
                        u16* __restrict__ wob) {
  const int total = 6291456;
  int i = blockIdx.x * blockDim.x + threadIdx.x;
  const int stride = gridDim.x * blockDim.x;
  for (; i < total; i += stride) {
    const int r = i >> 20;
    const float* src; u16* dst; int off;
    if (r < 2)       { src = x;  dst = xb;  off = i; }
    else if (r == 2) { src = wq; dst = wqb; off = i - (2 << 20); }
    else if (r == 3) { src = wk; dst = wkb; off = i - (3 << 20); }
    else if (r == 4) { src = wv; dst = wvb; off = i - (4 << 20); }
    else             { src = wo; dst = wob; off = i - (5 << 20); }
    float4 v = reinterpret_cast<const float4*>(src)[off];
    uint2 pk;
    pk.x = (uint32_t)f2bf(v.x) | ((uint32_t)f2bf(v.y) << 16);
    pk.y = (uint32_t)f2bf(v.z) | ((uint32_t)f2bf(v.w) << 16);
    reinterpret_cast<uint2*>(dst)[off] = pk;
  }
}

// ---------------- rope tables, interleaved {cos,sin} float2 ----------------
__global__ void rope_kernel(float2* __restrict__ rt) {
  const int i = blockIdx.x * blockDim.x + threadIdx.x;  // s*64 + f
  const int s = i >> 6, f = i & 63;
  const double inv = exp(-(double)f * (log(10000.0) / 64.0));
  const double a = (double)s * inv;
  rt[i] = make_float2((float)cos(a), (float)sin(a));
}

// ---------------- fused QKV GEMM: r3 champion structure (128x128, BK=64) ----------------
// grid (48,32): ct = blockIdx.x, region = ct>>4 (0 q, 1 k, 2 v), mt = blockIdx.y.
__global__ __launch_bounds__(256, 2)
void gemm_qkv(const u16* __restrict__ A,
              const u16* __restrict__ wqb, const u16* __restrict__ wkb,
              const u16* __restrict__ wvb,
              u16* __restrict__ qout, u16* __restrict__ kout, u16* __restrict__ vtout,
              const float2* __restrict__ rt) {
  constexpr int K = DMODEL;
  constexpr int BK = 64;
  __shared__ __align__(16) u16 As[128 * BK];
  __shared__ __align__(16) u16 Bs[128 * BK];
  const int region = blockIdx.x >> 4;
  const u16* Bw = region == 0 ? wqb : region == 1 ? wkb : wvb;
  const int tid = threadIdx.x;
  const int w = tid >> 6, lane = tid & 63;
  const int lr = lane & 15, lk = lane >> 4;
  const int wm = w >> 1, wn = w & 1;
  const int brow = blockIdx.y * 128;
  const int bcol = (blockIdx.x & 15) * 128;

  f32x4 acc[4][4] = {};

  const int st_row = w * 32 + (lane >> 3);
  const int st_col = (lane & 7) * 8;
  const u16* Ag = A  + (size_t)(brow + st_row) * K + st_col;
  const u16* Bg = Bw + (size_t)(bcol + st_row) * K + st_col;
  u16* AsW = As + w * 32 * BK;
  u16* BsW = Bs + w * 32 * BK;

  for (int k0 = 0; k0 < K; k0 += BK) {
#pragma unroll
    for (int i = 0; i < 4; ++i)
      __builtin_amdgcn_global_load_lds(
          (const AS1 void*)(Ag + (size_t)i * 8 * K + k0),
          (AS3 void*)(AsW + i * 8 * BK), 16, 0, 0);
#pragma unroll
    for (int i = 0; i < 4; ++i)
      __builtin_amdgcn_global_load_lds(
          (const AS1 void*)(Bg + (size_t)i * 8 * K + k0),
          (AS3 void*)(BsW + i * 8 * BK), 16, 0, 0);
    __syncthreads();
#pragma unroll
    for (int kc = 0; kc < 2; ++kc) {
      bf16x8 a[4], b[4];
#pragma unroll
      for (int m = 0; m < 4; ++m)
        a[m] = *reinterpret_cast<const bf16x8*>(&As[(wm * 64 + m * 16 + lr) * BK + kc * 32 + lk * 8]);
#pragma unroll
      for (int n = 0; n < 4; ++n)
        b[n] = *reinterpret_cast<const bf16x8*>(&Bs[(wn * 64 + n * 16 + lr) * BK + kc * 32 + lk * 8]);
#pragma unroll
      for (int m = 0; m < 4; ++m)
#pragma unroll
        for (int n = 0; n < 4; ++n)
          acc[m][n] = __builtin_amdgcn_mfma_f32_16x16x32_bf16(a[m], b[n], acc[m][n], 0, 0, 0);
    }
    __syncthreads();
  }

  if (region == 2) {            // V: write transposed [B,H,Dh,S] bf16
#pragma unroll
    for (int m = 0; m < 4; ++m) {
      const int gm0 = brow + wm * 64 + m * 16 + lk * 4;
      const int b = gm0 >> 11, s = gm0 & 2047;
#pragma unroll
      for (int n = 0; n < 4; ++n) {
        const int gn = bcol + wn * 64 + n * 16 + lr;
        const int h = gn >> 7, dh = gn & 127;
        uint2 pk;
        pk.x = (uint32_t)f2bf(acc[m][n][0]) | ((uint32_t)f2bf(acc[m][n][1]) << 16);
        pk.y = (uint32_t)f2bf(acc[m][n][2]) | ((uint32_t)f2bf(acc[m][n][3]) << 16);
        *reinterpret_cast<uint2*>(&vtout[((size_t)((b * NHEAD + h) * HDIM + dh)) * S_LEN + s]) = pk;
      }
    }
  } else {                      // Q/K: rope (+scale for Q), packed u32 stores
    u16* QK = region == 0 ? qout : kout;
#pragma unroll
    for (int m = 0; m < 4; ++m) {
      const int gm0 = brow + wm * 64 + m * 16 + lk * 4;
      const int b = gm0 >> 11, s0 = gm0 & 2047;
#pragma unroll
      for (int n = 0; n < 4; ++n) {
        const int gn = bcol + wn * 64 + n * 16 + lr;
        const int h = gn >> 7, dh = gn & 127;
        const int fi = dh >> 1;
        const bool ev = (dh & 1) == 0;
#pragma unroll
        for (int j = 0; j < 4; ++j) {
          float v = acc[m][n][j];
          float pp = __shfl_xor(v, 1, 64);        // partner channel (dh^1)
          const float2 cs = rt[(s0 + j) * 64 + fi];
          float oo = ev ? (v * cs.x - pp * cs.y) : (pp * cs.y + v * cs.x);
          if (region == 0) oo *= 0.08838834764831845f;   // Dh^-0.5
          const float op = __shfl_xor(oo, 1, 64); // partner's rope'd value
          if (ev) {
            const uint32_t pk = (uint32_t)f2bf(oo) | ((uint32_t)f2bf(op) << 16);
            *reinterpret_cast<uint32_t*>(
                &QK[((size_t)(b * NHEAD + h) * S_LEN + (s0 + j)) * HDIM + dh]) = pk;
          }
        }
      }
    }
  }
}

// ---------------- O projection: r3 champion 128x128 m97-structure ----------------
__global__ __launch_bounds__(256, 2)
void gemm_o(const u16* __restrict__ A, const u16* __restrict__ Bw,
            float* __restrict__ O) {
  constexpr int K = DMODEL;
  constexpr int BK = 64;
  __shared__ __align__(16) u16 As[128 * BK];
  __shared__ __align__(16) u16 Bs[128 * BK];
  const int tid = threadIdx.x;
  const int w = tid >> 6, lane = tid & 63;
  const int lr = lane & 15, lk = lane >> 4;
  const int wm = w >> 1, wn = w & 1;
  const int brow = blockIdx.y * 128;
  const int bcol = blockIdx.x * 128;

  f32x4 acc[4][4] = {};

  const int st_row = w * 32 + (lane >> 3);
  const int st_col = (lane & 7) * 8;
  const u16* Ag = A  + (size_t)(brow + st_row) * K + st_col;
  const u16* Bg = Bw + (size_t)(bcol + st_row) * K + st_col;
  u16* AsW = As + w * 32 * BK;
  u16* BsW = Bs + w * 32 * BK;

  for (int k0 = 0; k0 < K; k0 += BK) {
#pragma unroll
    for (int i = 0; i < 4; ++i)
      __builtin_amdgcn_global_load_lds(
          (const AS1 void*)(Ag + (size_t)i * 8 * K + k0),
          (AS3 void*)(AsW + i * 8 * BK), 16, 0, 0);
#pragma unroll
    for (int i = 0; i < 4; ++i)
      __builtin_amdgcn_global_load_lds(
          (const AS1 void*)(Bg + (size_t)i * 8 * K + k0),
          (AS3 void*)(BsW + i * 8 * BK), 16, 0, 0);
    __syncthreads();
#pragma unroll
    for (int kc = 0; kc < 2; ++kc) {
      bf16x8 a[4], b[4];
#pragma unroll
      for (int m = 0; m < 4; ++m)
        a[m] = *reinterpret_cast<const bf16x8*>(&As[(wm * 64 + m * 16 + lr) * BK + kc * 32 + lk * 8]);
#pragma unroll
      for (int n = 0; n < 4; ++n)
        b[n] = *reinterpret_cast<const bf16x8*>(&Bs[(wn * 64 + n * 16 + lr) * BK + kc * 32 + lk * 8]);
#pragma unroll
      for (int m = 0; m < 4; ++m)
#pragma unroll
        for (int n = 0; n < 4; ++n)
          acc[m][n] = __builtin_amdgcn_mfma_f32_16x16x32_bf16(a[m], b[n], acc[m][n], 0, 0, 0);
    }
    __syncthreads();
  }

#pragma unroll
  for (int m = 0; m < 4; ++m) {
    const int gm0 = brow + wm * 64 + m * 16 + lk * 4;
#pragma unroll
    for (int n = 0; n < 4; ++n) {
      const int gn = bcol + wn * 64 + n * 16 + lr;
#pragma unroll
      for (int j = 0; j < 4; ++j)
        O[(size_t)(gm0 + j) * DMODEL + gn] = acc[m][n][j];
    }
  }
}

// ---------------- sliding-window flash attention, LDS-staged K/V (r3-proven) ----------------
__global__ __launch_bounds__(256, 2)
void swa3_kernel(const u16* __restrict__ Qp, const u16* __restrict__ Kp,
                 const u16* __restrict__ Vt, u16* __restrict__ AO) {
  __shared__ __align__(16) u16 Ksh[2][64 * 128];
  __shared__ __align__(16) u16 Vsh[2][128 * 64];

  const int lin = blockIdx.x + gridDim.x * blockIdx.y;
  const int slot = lin >> 3;
  const int bh = (lin & 7) * 4 + (slot >> 4);
  const int qt = slot & 15;

  const int w = threadIdx.x >> 6;
  const int lane = threadIdx.x & 63;
  const int lq = lane & 31, hi = lane >> 5;
  const int qb_blk = qt * 128;
  const int qw = qb_blk + w * 32;
  const int qq = qw + lq;

  const u16* Qb = Qp + (size_t)bh * S_LEN * HDIM;
  const u16* Kb = Kp + (size_t)bh * S_LEN * HDIM;
  const u16* Vb = Vt + (size_t)bh * HDIM * S_LEN;

  bf16x8 qf[8];
#pragma unroll
  for (int s = 0; s < 8; ++s)
    qf[s] = *reinterpret_cast<const bf16x8*>(&Qb[(size_t)qq * HDIM + s * 16 + hi * 8]);

  f32x16 ot[4] = {};
  float m = 0.f, lsum = 0.f;

  const int c_lo = (qb_blk >= WIN) ? qb_blk - WIN : 0;
  const int c_hi = qb_blk + 128;

  auto stage = [&](int buf, int kc) {
#pragma unroll
    for (int i = 0; i < 4; ++i) {
      const int u = i * 256 + w * 64 + lane;
      const int row = u >> 4, sl = (u & 15) ^ (row & 7);
      __builtin_amdgcn_global_load_lds(
          (const AS1 void*)(Kb + (size_t)(kc + row) * HDIM + sl * 8),
          (AS3 void*)(&Ksh[buf][(size_t)(i * 256 + w * 64) * 8]), 16, 0, 0);
    }
#pragma unroll
    for (int i = 0; i < 4; ++i) {
      const int u = i * 256 + w * 64 + lane;
      const int row = u >> 3, sl = (u & 7) ^ (row & 7);
      __builtin_amdgcn_global_load_lds(
          (const AS1 void*)(Vb + (size_t)row * S_LEN + kc + sl * 8),
          (AS3 void*)(&Vsh[buf][(size_t)(i * 256 + w * 64) * 8]), 16, 0, 0);
    }
  };

  int buf = 0;
  stage(0, c_lo);
  __syncthreads();

  for (int kc = c_lo; kc < c_hi; kc += 64, buf ^= 1) {
    if (kc + 64 < c_hi) stage(buf ^ 1, kc + 64);

#pragma unroll
    for (int half = 0; half < 2; ++half) {
      const int kch = kc + half * 32;
      if (kch > qw + 31 || kch < qw - 542) continue;

      f32x16 P = {};
#pragma unroll
      for (int s = 0; s < 8; ++s) {
        const int row = half * 32 + lq;
        const int byte = row * 256 + ((s * 32 + hi * 16) ^ ((row & 7) << 4));
        bf16x8 kf = *reinterpret_cast<const bf16x8*>(&Ksh[buf][byte >> 1]);
        P = __builtin_amdgcn_mfma_f32_32x32x16_bf16(kf, qf[s], P, 0, 0, 0);
      }

      const bool needmask = (kch + 32 > qw) || (qw + 31 - kch >= WIN);
      float p[16];
      float pmax = -1e30f;
#pragma unroll
      for (int r = 0; r < 16; ++r) {
        float v = P[r];
        if (needmask) {
          const int kk = kch + (r & 3) + ((r >> 2) << 3) + hi * 4;
          const bool keep = (qq >= kk) && (qq - kk < WIN);
          v = keep ? v : -1e30f;
        }
        p[r] = v;
        pmax = fmaxf(pmax, v);
      }

      if (__any(pmax - m > 8.f)) {
        const float rm = fmaxf(pmax, __shfl_xor(pmax, 32, 64));
        const float mnew = fmaxf(m, rm);
        const float alpha = __expf(m - mnew);
        lsum *= alpha;
#pragma unroll
        for (int dt = 0; dt < 4; ++dt)
#pragma unroll
          for (int r = 0; r < 16; ++r) ot[dt][r] *= alpha;
        m = mnew;
      }

      float ls = 0.f;
#pragma unroll
      for (int r = 0; r < 16; ++r) {
        p[r] = __expf(p[r] - m);
        ls += p[r];
      }
      lsum += ls;

      uint32_t W[8];
#pragma unroll
      for (int i = 0; i < 8; ++i) W[i] = cvtpk(p[2 * i], p[2 * i + 1]);
      u32x2v r02 = __builtin_amdgcn_permlane32_swap(W[0], W[2], false, false);
      u32x2v r13 = __builtin_amdgcn_permlane32_swap(W[1], W[3], false, false);
      u32x2v r46 = __builtin_amdgcn_permlane32_swap(W[4], W[6], false, false);
      u32x2v r57 = __builtin_amdgcn_permlane32_swap(W[5], W[7], false, false);

#pragma unroll
      for (int ks = 0; ks < 2; ++ks) {
        union { uint32_t u[4]; bf16x8 v; } pb;
        if (ks == 0) { pb.u[0] = r02[0]; pb.u[1] = r13[0]; pb.u[2] = r02[1]; pb.u[3] = r13[1]; }
        else         { pb.u[0] = r46[0]; pb.u[1] = r57[0]; pb.u[2] = r46[1]; pb.u[3] = r57[1]; }
#pragma unroll
        for (int dt = 0; dt < 4; ++dt) {
          const int d = dt * 32 + lq;
          const int byte = d * 128 + ((half * 64 + ks * 32 + hi * 16) ^ ((d & 7) << 4));
          bf16x8 vf = *reinterpret_cast<const bf16x8*>(&Vsh[buf][byte >> 1]);
          ot[dt] = __builtin_amdgcn_mfma_f32_32x32x16_bf16(vf, pb.v, ot[dt], 0, 0, 0);
        }
      }
    }
    __syncthreads();
  }

  const float lf = lsum + __shfl_xor(lsum, 32, 64);
  const float inv = 1.f / lf;
  const int b = bh >> 4, h = bh & 15;
  u16* Ob = AO + (size_t)(b * S_LEN + qq) * DMODEL + h * HDIM;
#pragma unroll
  for (int dt = 0; dt < 4; ++dt)
#pragma unroll
    for (int rq = 0; rq < 4; ++rq) {
      uint2 pk;
      pk.x = cvtpk(ot[dt][rq * 4 + 0] * inv, ot[dt][rq * 4 + 1] * inv);
      pk.y = cvtpk(ot[dt][rq * 4 + 2] * inv, ot[dt][rq * 4 + 3] * inv);
      *reinterpret_cast<uint2*>(&Ob[dt * 32 + rq * 8 + hi * 4]) = pk;
    }
}

extern "C" void kernel_launch(void* const* d_in, const int* in_sizes, int n_in,
                              void* d_out, int out_size, void* d_ws, size_t ws_size,
                              hipStream_t stream) {
  const float* x  = (const float*)d_in[0];
  const float* Wq = (const float*)d_in[1];
  const float* Wk = (const float*)d_in[2];
  const float* Wv = (const float*)d_in[3];
  const float* Wo = (const float*)d_in[4];
  float* out = (float*)d_out;

  u16* p = (u16*)d_ws;
  u16* xb  = p; p += (size_t)4096 * 2048;
  u16* wqb = p; p += (size_t)2048 * 2048;
  u16* wkb = p; p += (size_t)2048 * 2048;
  u16* wvb = p; p += (size_t)2048 * 2048;
  u16* wob = p; p += (size_t)2048 * 2048;
  u16* qb  = p; p += (size_t)32 * 2048 * 128;   // [B,H,S,Dh]
  u16* kb  = p; p += (size_t)32 * 2048 * 128;   // [B,H,S,Dh]
  u16* vtb = p; p += (size_t)32 * 128 * 2048;   // [B,H,Dh,S]
  u16* aob = p; p += (size_t)4096 * 2048;       // [B*S, D]
  float2* rt = (float2*)p;

  cvt_all<<<3072, 256, 0, stream>>>(x, Wq, Wk, Wv, Wo, xb, wqb, wkb, wvb, wob);
  rope_kernel<<<512, 256, 0, stream>>>(rt);
  gemm_qkv<<<dim3(48, 32), 256, 0, stream>>>(xb, wqb, wkb, wvb, qb, kb, vtb, rt);
  swa3_kernel<<<dim3(16, 32), 256, 0, stream>>>(qb, kb, vtb, aob);
  gemm_o<<<dim3(16, 32), 256, 0, stream>>>(aob, wob, out);
}

// Round 11
// 228.614 us; speedup vs baseline: 1.5745x; 1.1402x over previous
//
#include <hip/hip_runtime.h>
#include <cstdint>
#include <cstddef>

typedef __bf16 bf16x8 __attribute__((ext_vector_type(8)));
typedef float f32x4 __attribute__((ext_vector_type(4)));
typedef float f32x16 __attribute__((ext_vector_type(16)));
typedef unsigned int u32x2v __attribute__((ext_vector_type(2)));
typedef unsigned short u16;

constexpr int S_LEN  = 2048;
constexpr int DMODEL = 2048;
constexpr int NHEAD  = 16;
constexpr int HDIM   = 128;
constexpr int WIN    = 512;

__device__ __forceinline__ u16 f2bf(float f) {
  union { float ff; uint32_t u; } a; a.ff = f;
  return (u16)((a.u + 0x7fffu + ((a.u >> 16) & 1u)) >> 16);  // RNE
}

__device__ __forceinline__ uint32_t cvtpk(float lo, float hi) {
  uint32_t r;
  asm("v_cvt_pk_bf16_f32 %0, %1, %2" : "=v"(r) : "v"(lo), "v"(hi));
  return r;
}

// ---------------- fused fp32 -> bf16 convert (x, Wq, Wk, Wv, Wo) ----------------
__global__ void cvt_all(const float* __restrict__ x,  const float* __restrict__ wq,
                        const float* __restrict__ wk, const float* __restrict__ wv,
                        const float* __restrict__ wo,
                        u16* __restrict__ xb,  u16* __restrict__ wqb,
                        u16* __restrict__ wkb, u16* __restrict__ wvb,
                        u16* __restrict__ wob) {
  const int total = 6291456;  // float4 count: x 2M, each W 1M
  int i = blockIdx.x * blockDim.x + threadIdx.x;
  const int stride = gridDim.x * blockDim.x;
  for (; i < total; i += stride) {
    const int r = i >> 20;
    const float* src; u16* dst; int off;
    if (r < 2)       { src = x;  dst = xb;  off = i; }
    else if (r == 2) { src = wq; dst = wqb; off = i - (2 << 20); }
    else if (r == 3) { src = wk; dst = wkb; off = i - (3 << 20); }
    else if (r == 4) { src = wv; dst = wvb; off = i - (4 << 20); }
    else             { src = wo; dst = wob; off = i - (5 << 20); }
    float4 v = reinterpret_cast<const float4*>(src)[off];
    uint2 pk;
    pk.x = (uint32_t)f2bf(v.x) | ((uint32_t)f2bf(v.y) << 16);
    pk.y = (uint32_t)f2bf(v.z) | ((uint32_t)f2bf(v.w) << 16);
    reinterpret_cast<uint2*>(dst)[off] = pk;
  }
}

// ---------------- rope tables (fp64 for accuracy, tiny) ----------------
__global__ void rope_kernel(float* __restrict__ rc, float* __restrict__ rs) {
  const int i = blockIdx.x * blockDim.x + threadIdx.x;  // s*64 + f
  const int s = i >> 6, f = i & 63;
  const double inv = exp(-(double)f * (log(10000.0) / 64.0));
  const double a = (double)s * inv;
  rc[i] = (float)cos(a);
  rs[i] = (float)sin(a);
}

// ---------------- fused QKV GEMM: region = blockIdx.x>>4 (0 q, 1 k, 2 v) ----------------
__global__ __launch_bounds__(256, 2)
void gemm_qkv(const u16* __restrict__ A,
              const u16* __restrict__ wqb, const u16* __restrict__ wkb,
              const u16* __restrict__ wvb,
              u16* __restrict__ qout, u16* __restrict__ kout, u16* __restrict__ vtout,
              const float* __restrict__ rc, const float* __restrict__ rs) {
  constexpr int K = DMODEL;
  constexpr int BK = 64;
  __shared__ __align__(16) u16 As[128 * BK];
  __shared__ __align__(16) u16 Bs[128 * BK];
  const int region = blockIdx.x >> 4;
  const u16* Bw = region == 0 ? wqb : region == 1 ? wkb : wvb;
  const int tid = threadIdx.x;
  const int w = tid >> 6, lane = tid & 63;
  const int lr = lane & 15, lk = lane >> 4;
  const int wm = w >> 1, wn = w & 1;
  const int brow = blockIdx.y * 128;
  const int bcol = (blockIdx.x & 15) * 128;   // region-local column

  f32x4 acc[4][4] = {};

  const int st_row = w * 32 + (lane >> 3);
  const int st_col = (lane & 7) * 8;
  const u16* Ag = A  + (size_t)(brow + st_row) * K + st_col;
  const u16* Bg = Bw + (size_t)(bcol + st_row) * K + st_col;
  u16* AsW = As + w * 32 * BK;
  u16* BsW = Bs + w * 32 * BK;

  for (int k0 = 0; k0 < K; k0 += BK) {
#pragma unroll
    for (int i = 0; i < 4; ++i)
      __builtin_amdgcn_global_load_lds(
          (const __attribute__((address_space(1))) void*)(Ag + (size_t)i * 8 * K + k0),
          (__attribute__((address_space(3))) void*)(AsW + i * 8 * BK), 16, 0, 0);
#pragma unroll
    for (int i = 0; i < 4; ++i)
      __builtin_amdgcn_global_load_lds(
          (const __attribute__((address_space(1))) void*)(Bg + (size_t)i * 8 * K + k0),
          (__attribute__((address_space(3))) void*)(BsW + i * 8 * BK), 16, 0, 0);
    __syncthreads();
#pragma unroll
    for (int kc = 0; kc < 2; ++kc) {
      bf16x8 a[4], b[4];
#pragma unroll
      for (int m = 0; m < 4; ++m)
        a[m] = *reinterpret_cast<const bf16x8*>(&As[(wm * 64 + m * 16 + lr) * BK + kc * 32 + lk * 8]);
#pragma unroll
      for (int n = 0; n < 4; ++n)
        b[n] = *reinterpret_cast<const bf16x8*>(&Bs[(wn * 64 + n * 16 + lr) * BK + kc * 32 + lk * 8]);
#pragma unroll
      for (int m = 0; m < 4; ++m)
#pragma unroll
        for (int n = 0; n < 4; ++n)
          acc[m][n] = __builtin_amdgcn_mfma_f32_16x16x32_bf16(a[m], b[n], acc[m][n], 0, 0, 0);
    }
    __syncthreads();
  }

  if (region == 2) {            // V: write transposed [B,H,Dh,S] bf16
#pragma unroll
    for (int m = 0; m < 4; ++m) {
      const int gm0 = brow + wm * 64 + m * 16 + lk * 4;
      const int b = gm0 >> 11, s = gm0 & 2047;
#pragma unroll
      for (int n = 0; n < 4; ++n) {
        const int gn = bcol + wn * 64 + n * 16 + lr;
        const int h = gn >> 7, dh = gn & 127;
        uint2 pk;
        pk.x = (uint32_t)f2bf(acc[m][n][0]) | ((uint32_t)f2bf(acc[m][n][1]) << 16);
        pk.y = (uint32_t)f2bf(acc[m][n][2]) | ((uint32_t)f2bf(acc[m][n][3]) << 16);
        *reinterpret_cast<uint2*>(&vtout[((size_t)((b * NHEAD + h) * HDIM + dh)) * S_LEN + s]) = pk;
      }
    }
  } else {                      // Q/K: rope (+scale for Q), [B,H,S,Dh] bf16
    u16* QK = region == 0 ? qout : kout;
#pragma unroll
    for (int m = 0; m < 4; ++m) {
      const int gm0 = brow + wm * 64 + m * 16 + lk * 4;
      const int b = gm0 >> 11, s0 = gm0 & 2047;
#pragma unroll
      for (int n = 0; n < 4; ++n) {
        const int gn = bcol + wn * 64 + n * 16 + lr;
        const int h = gn >> 7, dh = gn & 127;
        const int fi = dh >> 1;
        const bool ev = (dh & 1) == 0;
#pragma unroll
        for (int j = 0; j < 4; ++j) {
          float v = acc[m][n][j];
          float pp = __shfl_xor(v, 1, 64);        // partner channel (dh^1)
          const float c  = rc[(s0 + j) * 64 + fi];
          const float sn = rs[(s0 + j) * 64 + fi];
          float oo = ev ? (v * c - pp * sn) : (pp * sn + v * c);
          if (region == 0) oo *= 0.08838834764831845f;   // Dh^-0.5
          QK[((size_t)(b * NHEAD + h) * S_LEN + (s0 + j)) * HDIM + dh] = f2bf(oo);
        }
      }
    }
  }
}

// ---------------- plain GEMM for the Wo projection (fp32 out) ----------------
__global__ __launch_bounds__(256, 2)
void gemm_o(const u16* __restrict__ A, const u16* __restrict__ Bw,
            float* __restrict__ O) {
  constexpr int K = DMODEL;
  constexpr int BK = 64;
  __shared__ __align__(16) u16 As[128 * BK];
  __shared__ __align__(16) u16 Bs[128 * BK];
  const int tid = threadIdx.x;
  const int w = tid >> 6, lane = tid & 63;
  const int lr = lane & 15, lk = lane >> 4;
  const int wm = w >> 1, wn = w & 1;
  const int brow = blockIdx.y * 128;
  const int bcol = blockIdx.x * 128;

  f32x4 acc[4][4] = {};

  const int st_row = w * 32 + (lane >> 3);
  const int st_col = (lane & 7) * 8;
  const u16* Ag = A  + (size_t)(brow + st_row) * K + st_col;
  const u16* Bg = Bw + (size_t)(bcol + st_row) * K + st_col;
  u16* AsW = As + w * 32 * BK;
  u16* BsW = Bs + w * 32 * BK;

  for (int k0 = 0; k0 < K; k0 += BK) {
#pragma unroll
    for (int i = 0; i < 4; ++i)
      __builtin_amdgcn_global_load_lds(
          (const __attribute__((address_space(1))) void*)(Ag + (size_t)i * 8 * K + k0),
          (__attribute__((address_space(3))) void*)(AsW + i * 8 * BK), 16, 0, 0);
#pragma unroll
    for (int i = 0; i < 4; ++i)
      __builtin_amdgcn_global_load_lds(
          (const __attribute__((address_space(1))) void*)(Bg + (size_t)i * 8 * K + k0),
          (__attribute__((address_space(3))) void*)(BsW + i * 8 * BK), 16, 0, 0);
    __syncthreads();
#pragma unroll
    for (int kc = 0; kc < 2; ++kc) {
      bf16x8 a[4], b[4];
#pragma unroll
      for (int m = 0; m < 4; ++m)
        a[m] = *reinterpret_cast<const bf16x8*>(&As[(wm * 64 + m * 16 + lr) * BK + kc * 32 + lk * 8]);
#pragma unroll
      for (int n = 0; n < 4; ++n)
        b[n] = *reinterpret_cast<const bf16x8*>(&Bs[(wn * 64 + n * 16 + lr) * BK + kc * 32 + lk * 8]);
#pragma unroll
      for (int m = 0; m < 4; ++m)
#pragma unroll
        for (int n = 0; n < 4; ++n)
          acc[m][n] = __builtin_amdgcn_mfma_f32_16x16x32_bf16(a[m], b[n], acc[m][n], 0, 0, 0);
    }
    __syncthreads();
  }

#pragma unroll
  for (int m = 0; m < 4; ++m) {
    const int gm0 = brow + wm * 64 + m * 16 + lk * 4;
#pragma unroll
    for (int n = 0; n < 4; ++n) {
      const int gn = bcol + wn * 64 + n * 16 + lr;
#pragma unroll
      for (int j = 0; j < 4; ++j)
        O[(size_t)(gm0 + j) * DMODEL + gn] = acc[m][n][j];
    }
  }
}

// ---------------- sliding-window flash attention, LDS-staged K/V ----------------
// Block = 4 waves x 32 q rows = 128 rows. K/V staged per 64-key chunk, double-buffered,
// XOR-swizzled (pre-swizzled global source + swizzled ds_read). Softmax in-register.
__global__ __launch_bounds__(256, 2)
void swa3_kernel(const u16* __restrict__ Qp, const u16* __restrict__ Kp,
                 const u16* __restrict__ Vt, u16* __restrict__ AO) {
  __shared__ __align__(16) u16 Ksh[2][64 * 128];    // [64 keys][128 dh], rows 256B, swizzled
  __shared__ __align__(16) u16 Vsh[2][128 * 64];    // [128 dh][64 keys], rows 128B, swizzled

  // XCD swizzle: 16 q-tiles of one bh contiguous; 4 bh per XCD (K+V 4MB = one L2)
  const int lin = blockIdx.x + gridDim.x * blockIdx.y;   // 0..511
  const int slot = lin >> 3;
  const int bh = (lin & 7) * 4 + (slot >> 4);
  const int qt = slot & 15;

  const int w = threadIdx.x >> 6;
  const int lane = threadIdx.x & 63;
  const int lq = lane & 31, hi = lane >> 5;
  const int qb_blk = qt * 128;
  const int qw = qb_blk + w * 32;                 // this wave's 32 q rows
  const int qq = qw + lq;

  const u16* Qb = Qp + (size_t)bh * S_LEN * HDIM;
  const u16* Kb = Kp + (size_t)bh * S_LEN * HDIM;
  const u16* Vb = Vt + (size_t)bh * HDIM * S_LEN;

  // Q fragments (B-operand): qf[s] = Q[qw+lq][s*16 + hi*8 + j]
  bf16x8 qf[8];
#pragma unroll
  for (int s = 0; s < 8; ++s)
    qf[s] = *reinterpret_cast<const bf16x8*>(&Qb[(size_t)qq * HDIM + s * 16 + hi * 8]);

  f32x16 ot[4] = {};          // O^T: d = dt*32 + (r&3)+8*(r>>2)+4*hi, q = lq
  float m = 0.f, lsum = 0.f;

  const int c_lo = (qb_blk >= WIN) ? qb_blk - WIN : 0;
  const int c_hi = qb_blk + 128;

  // stage 64-key chunk kc into buffer buf (pre-swizzled source, linear LDS dest)
  auto stage = [&](int buf, int kc) {
#pragma unroll
    for (int i = 0; i < 4; ++i) {       // K: 1024 16B-units, 16 units/row
      const int u = i * 256 + w * 64 + lane;
      const int row = u >> 4, sl = (u & 15) ^ (row & 7);
      __builtin_amdgcn_global_load_lds(
          (const __attribute__((address_space(1))) void*)(Kb + (size_t)(kc + row) * HDIM + sl * 8),
          (__attribute__((address_space(3))) void*)(&Ksh[buf][(size_t)(i * 256 + w * 64) * 8]),
          16, 0, 0);
    }
#pragma unroll
    for (int i = 0; i < 4; ++i) {       // V: 1024 16B-units, 8 units/row
      const int u = i * 256 + w * 64 + lane;
      const int row = u >> 3, sl = (u & 7) ^ (row & 7);
      __builtin_amdgcn_global_load_lds(
          (const __attribute__((address_space(1))) void*)(Vb + (size_t)row * S_LEN + kc + sl * 8),
          (__attribute__((address_space(3))) void*)(&Vsh[buf][(size_t)(i * 256 + w * 64) * 8]),
          16, 0, 0);
    }
  };

  int buf = 0;
  stage(0, c_lo);
  __syncthreads();

  for (int kc = c_lo; kc < c_hi; kc += 64, buf ^= 1) {
    if (kc + 64 < c_hi) stage(buf ^ 1, kc + 64);

#pragma unroll
    for (int half = 0; half < 2; ++half) {
      const int kch = kc + half * 32;
      if (kch > qw + 31 || kch < qw - 542) continue;   // wave-uniform skip

      // QK^T: P[k][q], k-row = (r&3)+8*(r>>2)+4*hi, q-col = lq
      f32x16 P = {};
#pragma unroll
      for (int s = 0; s < 8; ++s) {
        const int row = half * 32 + lq;
        const int byte = row * 256 + ((s * 32 + hi * 16) ^ ((row & 7) << 4));
        bf16x8 kf = *reinterpret_cast<const bf16x8*>(&Ksh[buf][byte >> 1]);
        P = __builtin_amdgcn_mfma_f32_32x32x16_bf16(kf, qf[s], P, 0, 0, 0);
      }

      const bool needmask = (kch + 32 > qw) || (qw + 31 - kch >= WIN);
      float p[16];
      float pmax = -1e30f;
#pragma unroll
      for (int r = 0; r < 16; ++r) {
        float v = P[r];
        if (needmask) {
          const int kk = kch + (r & 3) + ((r >> 2) << 3) + hi * 4;
          const bool keep = (qq >= kk) && (qq - kk < WIN);
          v = keep ? v : -1e30f;
        }
        p[r] = v;
        pmax = fmaxf(pmax, v);
      }

      // T13 defer-max
      if (__any(pmax - m > 8.f)) {
        const float rm = fmaxf(pmax, __shfl_xor(pmax, 32, 64));
        const float mnew = fmaxf(m, rm);
        const float alpha = __expf(m - mnew);
        lsum *= alpha;
#pragma unroll
        for (int dt = 0; dt < 4; ++dt)
#pragma unroll
          for (int r = 0; r < 16; ++r) ot[dt][r] *= alpha;
        m = mnew;
      }

      float ls = 0.f;
#pragma unroll
      for (int r = 0; r < 16; ++r) {
        p[r] = __expf(p[r] - m);
        ls += p[r];
      }
      lsum += ls;

      // T12: pack to bf16 + permlane redistribute into PV B-fragments
      uint32_t W[8];
#pragma unroll
      for (int i = 0; i < 8; ++i) W[i] = cvtpk(p[2 * i], p[2 * i + 1]);
      u32x2v r02 = __builtin_amdgcn_permlane32_swap(W[0], W[2], false, false);
      u32x2v r13 = __builtin_amdgcn_permlane32_swap(W[1], W[3], false, false);
      u32x2v r46 = __builtin_amdgcn_permlane32_swap(W[4], W[6], false, false);
      u32x2v r57 = __builtin_amdgcn_permlane32_swap(W[5], W[7], false, false);

#pragma unroll
      for (int ks = 0; ks < 2; ++ks) {
        union { uint32_t u[4]; bf16x8 v; } pb;
        if (ks == 0) { pb.u[0] = r02[0]; pb.u[1] = r13[0]; pb.u[2] = r02[1]; pb.u[3] = r13[1]; }
        else         { pb.u[0] = r46[0]; pb.u[1] = r57[0]; pb.u[2] = r46[1]; pb.u[3] = r57[1]; }
#pragma unroll
        for (int dt = 0; dt < 4; ++dt) {
          const int d = dt * 32 + lq;
          const int byte = d * 128 + ((half * 64 + ks * 32 + hi * 16) ^ ((d & 7) << 4));
          bf16x8 vf = *reinterpret_cast<const bf16x8*>(&Vsh[buf][byte >> 1]);
          ot[dt] = __builtin_amdgcn_mfma_f32_32x32x16_bf16(vf, pb.v, ot[dt], 0, 0, 0);
        }
      }
    }
    __syncthreads();   // staging of next chunk done + all waves done reading buf
  }

  const float lf = lsum + __shfl_xor(lsum, 32, 64);
  const float inv = 1.f / lf;
  const int b = bh >> 4, h = bh & 15;
  u16* Ob = AO + (size_t)(b * S_LEN + qq) * DMODEL + h * HDIM;
#pragma unroll
  for (int dt = 0; dt < 4; ++dt)
#pragma unroll
    for (int rq = 0; rq < 4; ++rq) {
      uint2 pk;
      pk.x = cvtpk(ot[dt][rq * 4 + 0] * inv, ot[dt][rq * 4 + 1] * inv);
      pk.y = cvtpk(ot[dt][rq * 4 + 2] * inv, ot[dt][rq * 4 + 3] * inv);
      *reinterpret_cast<uint2*>(&Ob[dt * 32 + rq * 8 + hi * 4]) = pk;
    }
}

extern "C" void kernel_launch(void* const* d_in, const int* in_sizes, int n_in,
                              void* d_out, int out_size, void* d_ws, size_t ws_size,
                              hipStream_t stream) {
  const float* x  = (const float*)d_in[0];
  const float* Wq = (const float*)d_in[1];
  const float* Wk = (const float*)d_in[2];
  const float* Wv = (const float*)d_in[3];
  const float* Wo = (const float*)d_in[4];
  float* out = (float*)d_out;

  u16* p = (u16*)d_ws;
  u16* xb  = p; p += (size_t)4096 * 2048;
  u16* wqb = p; p += (size_t)2048 * 2048;
  u16* wkb = p; p += (size_t)2048 * 2048;
  u16* wvb = p; p += (size_t)2048 * 2048;
  u16* wob = p; p += (size_t)2048 * 2048;
  u16* qb  = p; p += (size_t)32 * 2048 * 128;   // [B,H,S,Dh]
  u16* kb  = p; p += (size_t)32 * 2048 * 128;   // [B,H,S,Dh]
  u16* vtb = p; p += (size_t)32 * 128 * 2048;   // [B,H,Dh,S]
  u16* aob = p; p += (size_t)4096 * 2048;       // [B*S, D]
  float* rc = (float*)p;
  float* rs = rc + (size_t)2048 * 64;

  cvt_all<<<3072, 256, 0, stream>>>(x, Wq, Wk, Wv, Wo, xb, wqb, wkb, wvb, wob);
  rope_kernel<<<512, 256, 0, stream>>>(rc, rs);
  gemm_qkv<<<dim3(48, 32), 256, 0, stream>>>(xb, wqb, wkb, wvb, qb, kb, vtb, rc, rs);
  swa3_kernel<<<dim3(16, 32), 256, 0, stream>>>(qb, kb, vtb, aob);
  gemm_o<<<dim3(16, 32), 256, 0, stream>>>(aob, wob, out);
}